// Round 6
// baseline (164.011 us; speedup 1.0000x reference)
//
#include <hip/hip_runtime.h>
#include <hip/hip_bf16.h>

// Problem: B=2048, D=512, all fp32.
// q = query@Wq.T+bq ; k,v likewise. attn[b,i,j]=q_i*k_j (rank-1!),
// softmax over j, out[b,i] = sum_j softmax_j(q_i*k_j)*v_j.
//
// Round 6 (controlled): attn = round-4 code exactly (76.4 us reference).
// gemm v3: in-kernel split-bf16 MFMA, double-buffered LDS, ONE barrier/iter,
// global loads issued 2 iterations ahead. No presplit, ws need = 12.58 MB.

#define B_SZ 2048
#define D_SZ 512

typedef __attribute__((ext_vector_type(2))) float  f32x2;
typedef __attribute__((ext_vector_type(4))) float  f32x4;
typedef __attribute__((ext_vector_type(8))) short  bf16x8;   // MFMA A/B carrier
typedef __attribute__((ext_vector_type(8))) unsigned short u16x8;

__device__ __forceinline__ float exp2_raw(float x) {
#if defined(__has_builtin) && __has_builtin(__builtin_amdgcn_exp2f)
    return __builtin_amdgcn_exp2f(x);
#else
    return exp2f(x);
#endif
}

// Truncation split: hi = top 16 bits of fp32; lo = bf16(trunc) of residual.
// |x - hi - lo| <= 2^-14 |x|
__device__ __forceinline__ void split1(float x, unsigned short& hi, unsigned short& lo) {
    unsigned int u = __float_as_uint(x);
    hi = (unsigned short)(u >> 16);
    float r = x - __uint_as_float(u & 0xFFFF0000u);
    lo = (unsigned short)(__float_as_uint(r) >> 16);
}

// 8 consecutive floats (two float4) -> hi/lo u16x8
__device__ __forceinline__ void split8(const float4& a, const float4& b,
                                       u16x8& h, u16x8& l) {
    unsigned short hh, ll;
    split1(a.x, hh, ll); h[0] = hh; l[0] = ll;
    split1(a.y, hh, ll); h[1] = hh; l[1] = ll;
    split1(a.z, hh, ll); h[2] = hh; l[2] = ll;
    split1(a.w, hh, ll); h[3] = hh; l[3] = ll;
    split1(b.x, hh, ll); h[4] = hh; l[4] = ll;
    split1(b.y, hh, ll); h[5] = hh; l[5] = ll;
    split1(b.z, hh, ll); h[6] = hh; l[6] = ll;
    split1(b.w, hh, ll); h[7] = hh; l[7] = ll;
}

// ---------------------------------------------------------------------------
// GEMM v3: Y = X @ W^T + bias, split-bf16 MFMA, blockIdx.z selects q/k/v.
// 64x64 tile, 256 thr (4 waves 2x2), BK=32, 16 K-iters.
// Double-buffered LDS, one barrier per iter, loads 2 iters ahead.
// Staging: thread t -> row sr=t>>2, 8-float chunk sc=(t&3)*8; loads 2 float4,
// splits once, stores 4x b128. LDS rows padded to 40 shorts (group-step 5,
// coprime 8 -> uniform bank-group spread for b128 frag reads).
// ---------------------------------------------------------------------------
__global__ __launch_bounds__(256) void qkv_gemm_v3(
    const float* __restrict__ Xq, const float* __restrict__ Xk, const float* __restrict__ Xv,
    const float* __restrict__ Wq, const float* __restrict__ bq,
    const float* __restrict__ Wk, const float* __restrict__ bk,
    const float* __restrict__ Wv, const float* __restrict__ bv,
    float* __restrict__ qkv_out)
{
    const int which = blockIdx.z;
    const float* __restrict__ X    = (which == 0) ? Xq : (which == 1) ? Xk : Xv;
    const float* __restrict__ W    = (which == 0) ? Wq : (which == 1) ? Wk : Wv;
    const float* __restrict__ bias = (which == 0) ? bq : (which == 1) ? bk : bv;
    float* __restrict__ Y = qkv_out + (size_t)which * B_SZ * D_SZ;

    const int t    = threadIdx.x;
    const int lane = t & 63;
    const int wv   = t >> 6;
    const int l15  = lane & 15;
    const int quad = lane >> 4;
    const int wm   = (wv >> 1) * 32;
    const int wn   = (wv & 1) * 32;
    const int m0   = blockIdx.x * 64;
    const int n0   = blockIdx.y * 64;

    __shared__ unsigned short AsH[2][64][40], AsL[2][64][40];
    __shared__ unsigned short BsH[2][64][40], BsL[2][64][40];

    f32x4 acc[2][2] = {{{0.f,0.f,0.f,0.f},{0.f,0.f,0.f,0.f}},
                       {{0.f,0.f,0.f,0.f},{0.f,0.f,0.f,0.f}}};

    const int sr = t >> 2;            // 0..63
    const int sc = (t & 3) * 8;       // 0,8,16,24 (floats == shorts index)
    const float* pX = &X[(size_t)(m0 + sr) * D_SZ + sc];
    const float* pW = &W[(size_t)(n0 + sr) * D_SZ + sc];

    float4 xa, xb, wa, wb;            // in-flight global loads (8 floats each op)
    u16x8 xh, xl, wh, wl;

#define LOADC(kpos)  do { \
        xa = *(const float4*)(pX + (kpos)); \
        xb = *(const float4*)(pX + (kpos) + 4); \
        wa = *(const float4*)(pW + (kpos)); \
        wb = *(const float4*)(pW + (kpos) + 4); } while (0)
#define SPLITC()     do { split8(xa, xb, xh, xl); split8(wa, wb, wh, wl); } while (0)
#define STOREC(bf)   do { \
        *(u16x8*)&AsH[bf][sr][sc] = xh; \
        *(u16x8*)&AsL[bf][sr][sc] = xl; \
        *(u16x8*)&BsH[bf][sr][sc] = wh; \
        *(u16x8*)&BsL[bf][sr][sc] = wl; } while (0)

    LOADC(0);
    SPLITC();
    STOREC(0);
    LOADC(32);
    __syncthreads();

    for (int kc = 0; kc < 16; ++kc) {
        const int cur = kc & 1;

        bf16x8 ah0 = *(const bf16x8*)&AsH[cur][wm + l15     ][quad * 8];
        bf16x8 ah1 = *(const bf16x8*)&AsH[cur][wm + 16 + l15][quad * 8];
        bf16x8 al0 = *(const bf16x8*)&AsL[cur][wm + l15     ][quad * 8];
        bf16x8 al1 = *(const bf16x8*)&AsL[cur][wm + 16 + l15][quad * 8];
        bf16x8 bh0 = *(const bf16x8*)&BsH[cur][wn + l15     ][quad * 8];
        bf16x8 bh1 = *(const bf16x8*)&BsH[cur][wn + 16 + l15][quad * 8];
        bf16x8 bl0 = *(const bf16x8*)&BsL[cur][wn + l15     ][quad * 8];
        bf16x8 bl1 = *(const bf16x8*)&BsL[cur][wn + 16 + l15][quad * 8];

        if (kc + 1 < 16) { SPLITC(); STOREC(1 - cur); }   // regs loaded last iter
        if (kc + 2 < 16) LOADC((kc + 2) * 32);            // 2 iters ahead

        acc[0][0] = __builtin_amdgcn_mfma_f32_16x16x32_bf16(ah0, bh0, acc[0][0], 0, 0, 0);
        acc[0][1] = __builtin_amdgcn_mfma_f32_16x16x32_bf16(ah0, bh1, acc[0][1], 0, 0, 0);
        acc[1][0] = __builtin_amdgcn_mfma_f32_16x16x32_bf16(ah1, bh0, acc[1][0], 0, 0, 0);
        acc[1][1] = __builtin_amdgcn_mfma_f32_16x16x32_bf16(ah1, bh1, acc[1][1], 0, 0, 0);
        acc[0][0] = __builtin_amdgcn_mfma_f32_16x16x32_bf16(al0, bh0, acc[0][0], 0, 0, 0);
        acc[0][1] = __builtin_amdgcn_mfma_f32_16x16x32_bf16(al0, bh1, acc[0][1], 0, 0, 0);
        acc[1][0] = __builtin_amdgcn_mfma_f32_16x16x32_bf16(al1, bh0, acc[1][0], 0, 0, 0);
        acc[1][1] = __builtin_amdgcn_mfma_f32_16x16x32_bf16(al1, bh1, acc[1][1], 0, 0, 0);
        acc[0][0] = __builtin_amdgcn_mfma_f32_16x16x32_bf16(ah0, bl0, acc[0][0], 0, 0, 0);
        acc[0][1] = __builtin_amdgcn_mfma_f32_16x16x32_bf16(ah0, bl1, acc[0][1], 0, 0, 0);
        acc[1][0] = __builtin_amdgcn_mfma_f32_16x16x32_bf16(ah1, bl0, acc[1][0], 0, 0, 0);
        acc[1][1] = __builtin_amdgcn_mfma_f32_16x16x32_bf16(ah1, bl1, acc[1][1], 0, 0, 0);

        __syncthreads();
    }
#undef LOADC
#undef SPLITC
#undef STOREC

    // epilogue: C/D layout col=lane&15, row=quad*4+reg (m89/m91-verified)
#pragma unroll
    for (int ni = 0; ni < 2; ++ni) {
        const int col = n0 + wn + ni * 16 + l15;
        const float bb = bias[col];
#pragma unroll
        for (int mi = 0; mi < 2; ++mi) {
            const int row = m0 + wm + mi * 16 + quad * 4;
#pragma unroll
            for (int r = 0; r < 4; ++r) {
                Y[(size_t)(row + r) * D_SZ + col] = acc[mi][ni][r] + bb;
            }
        }
    }
}

// ---------------------------------------------------------------------------
// attn (round-4 control, 76.4 us): out[b,i] = sum_j exp(q_i*k_j - m_i)*v_j/den,
// m_i via kmax/kmin (exact rank-1 row max). log2 domain. One block per b,
// 256 thr, 2 rows/thread, (k,v) interleaved in LDS read as float4 (2 j's).
// ---------------------------------------------------------------------------
__global__ __launch_bounds__(256) void attn_kernel(
    const float* __restrict__ qkv, float* __restrict__ out)
{
    const int b = blockIdx.x;
    const int t = threadIdx.x;

    const float* __restrict__ q = qkv + (size_t)b * D_SZ;
    const float* __restrict__ k = qkv + (size_t)B_SZ * D_SZ + (size_t)b * D_SZ;
    const float* __restrict__ v = qkv + (size_t)2 * B_SZ * D_SZ + (size_t)b * D_SZ;

    __shared__ float kv[D_SZ * 2];          // interleaved: k0*L,v0,k1*L,v1,...
    __shared__ float redmax[4], redmin[4];

    const float L = 1.44269504088896340736f;  // log2(e)

    const int i0 = t, i1 = t + 256;
    const float q0 = q[i0];
    const float q1 = q[i1];

    float kmaxL = -3.0e38f, kminL = 3.0e38f;
#pragma unroll
    for (int j = t; j < D_SZ; j += 256) {
        float kj = k[j] * L;
        float vj = v[j];
        *(float2*)&kv[2 * j] = make_float2(kj, vj);
        kmaxL = fmaxf(kmaxL, kj);
        kminL = fminf(kminL, kj);
    }
#pragma unroll
    for (int off = 32; off > 0; off >>= 1) {
        kmaxL = fmaxf(kmaxL, __shfl_xor(kmaxL, off));
        kminL = fminf(kminL, __shfl_xor(kminL, off));
    }
    const int wave = t >> 6;
    if ((t & 63) == 0) { redmax[wave] = kmaxL; redmin[wave] = kminL; }
    __syncthreads();   // also publishes kv[]
    kmaxL = fmaxf(fmaxf(redmax[0], redmax[1]), fmaxf(redmax[2], redmax[3]));
    kminL = fminf(fminf(redmin[0], redmin[1]), fminf(redmin[2], redmin[3]));

    const float c0 = (q0 >= 0.f) ? -(q0 * kmaxL) : -(q0 * kminL);
    const float c1 = (q1 >= 0.f) ? -(q1 * kmaxL) : -(q1 * kminL);

    f32x2 den_a = {0.f, 0.f}, den_b = {0.f, 0.f};
    f32x2 num_a = {0.f, 0.f}, num_b = {0.f, 0.f};
#pragma unroll 8
    for (int j = 0; j < D_SZ; j += 2) {
        f32x4 p = *(const f32x4*)&kv[2 * j];   // kL_j, v_j, kL_{j+1}, v_{j+1}
        float e0a = exp2_raw(fmaf(q0, p.x, c0));
        float e1a = exp2_raw(fmaf(q1, p.x, c1));
        float e0b = exp2_raw(fmaf(q0, p.z, c0));
        float e1b = exp2_raw(fmaf(q1, p.z, c1));
        f32x2 ea = {e0a, e1a};
        f32x2 eb = {e0b, e1b};
        f32x2 va = {p.y, p.y};
        f32x2 vb = {p.w, p.w};
        den_a += ea;
        den_b += eb;
        num_a += ea * va;
        num_b += eb * vb;
    }
    const f32x2 den = den_a + den_b;
    const f32x2 num = num_a + num_b;
    out[(size_t)b * D_SZ + i0] = num.x / den.x;
    out[(size_t)b * D_SZ + i1] = num.y / den.y;
}

extern "C" void kernel_launch(void* const* d_in, const int* in_sizes, int n_in,
                              void* d_out, int out_size, void* d_ws, size_t ws_size,
                              hipStream_t stream) {
    const float* query = (const float*)d_in[0];
    const float* key_  = (const float*)d_in[1];
    const float* value = (const float*)d_in[2];
    const float* Wq    = (const float*)d_in[3];
    const float* bq    = (const float*)d_in[4];
    const float* Wk    = (const float*)d_in[5];
    const float* bk    = (const float*)d_in[6];
    const float* Wv    = (const float*)d_in[7];
    const float* bv    = (const float*)d_in[8];
    float* out = (float*)d_out;

    float* qkv = (float*)d_ws;  // [3][B][D] fp32 = 12.58 MB (proven available)

    dim3 g1(B_SZ / 64, D_SZ / 64, 3);
    qkv_gemm_v3<<<g1, 256, 0, stream>>>(query, key_, value, Wq, bq, Wk, bk, Wv, bv, qkv);
    attn_kernel<<<B_SZ, 256, 0, stream>>>(qkv, out);
}